// Round 20
// baseline (361.407 us; speedup 1.0000x reference)
//
#include <hip/hip_runtime.h>
#include <hip/hip_fp16.h>

#define DEVINL __device__ __forceinline__

static constexpr int Bn = 2048;
static constexpr int Sn = 256;
static constexpr long long BSn = (long long)Bn * Sn;  // 524288

typedef _Float16 h2v __attribute__((ext_vector_type(2)));
typedef _Float16 half8 __attribute__((ext_vector_type(8)));
typedef float floatx4 __attribute__((ext_vector_type(4)));

DEVINL float dot2(unsigned int a, unsigned int b, float c) {
#if __has_builtin(__builtin_amdgcn_fdot2)
    return __builtin_amdgcn_fdot2(__builtin_bit_cast(h2v, a), __builtin_bit_cast(h2v, b), c, false);
#else
    __half2 ha = __builtin_bit_cast(__half2, a);
    __half2 hb = __builtin_bit_cast(__half2, b);
    return c + __low2float(ha) * __low2float(hb) + __high2float(ha) * __high2float(hb);
#endif
}
DEVINL unsigned int packh2(float a, float b) {
    __half2 h = __floats2half2_rn(a, b);
    return __builtin_bit_cast(unsigned int, h);
}
DEVINL unsigned short f2h16(float f) { return __builtin_bit_cast(unsigned short, (_Float16)f); }
DEVINL float h16f(unsigned short u) { return (float)__builtin_bit_cast(_Float16, u); }
DEVINL float sigmoidf_(float x) { return 1.0f / (1.0f + __expf(-x)); }
DEVINL float tanhf_(float x) { return 2.0f / (1.0f + __expf(-2.0f * x)) - 1.0f; }

// ---- packed-weight workspace layout (byte offsets, after X and hseq) ----
enum {
    WP_K1_FRAG = 0,        // 14 arrays * [256] half8
    WP_K1_BIAS = 57344,    // 2 arrays * [256] float4
    WP_K2_FRAG = 65536,    // 12 arrays * [512] half8
    WP_K2_BIAS = 163840,   // [512] float2
    WP_K4_FRAG = 167936,   // 2 arrays * [256] half8
    WP_K4_BIAS = 176128,   // [256] float
    WP_TOTAL = 177152
};

// ================= k0: one-shot weight fragment packing (grid 6) =================
__global__ __launch_bounds__(512) void k0_pack(
    const float* __restrict__ pe_w1, const float* __restrict__ pe_b1,
    const float* __restrict__ pe_w2, const float* __restrict__ pe_b2,
    const float* __restrict__ ee_w1, const float* __restrict__ ee_b1,
    const float* __restrict__ ee_w2, const float* __restrict__ ee_b2,
    const float* __restrict__ cb_w1, const float* __restrict__ cb_b1,
    const float* __restrict__ cb_w2, const float* __restrict__ cb_b2,
    const float* __restrict__ ih_w, const float* __restrict__ ih_b,
    const float* __restrict__ hh_w, const float* __restrict__ hh_b,
    const float* __restrict__ th_w, const float* __restrict__ th_b,
    const float* __restrict__ an_w, const float* __restrict__ an_b,
    const float* __restrict__ sh_w, const float* __restrict__ sh_b,
    const float* __restrict__ bo_w, const float* __restrict__ bo_b,
    char* __restrict__ Wp)
{
    const int t = threadIdx.x;
    const int bk = blockIdx.x;
    half8* f1 = (half8*)(Wp + WP_K1_FRAG);
    float4* b1v = (float4*)(Wp + WP_K1_BIAS);
    half8* f2 = (half8*)(Wp + WP_K2_FRAG);
    float2* b2v = (float2*)(Wp + WP_K2_BIAS);
    half8* f4 = (half8*)(Wp + WP_K4_FRAG);
    float* b4v = (float*)(Wp + WP_K4_BIAS);

    if (bk == 0) {
        if (t >= 256) return;
        const int l = t & 63, w = t >> 6;
        const int kof = (l >> 4) * 8;
        const int c16 = w * 16 + (l & 15);
        #pragma unroll
        for (int ct = 0; ct < 2; ct++) {
            int col = w * 32 + ct * 16 + (l & 15);
            #pragma unroll
            for (int kt = 0; kt < 2; kt++) {
                half8 v;
                #pragma unroll
                for (int j = 0; j < 8; j++) { int k = kt * 32 + kof + j; v[j] = (k < 63) ? (_Float16)cb_w1[k * 128 + col] : (_Float16)0.f; }
                f1[(ct * 2 + kt) * 256 + t] = v;
            }
        }
        #pragma unroll
        for (int kt = 0; kt < 4; kt++) {
            half8 v;
            #pragma unroll
            for (int j = 0; j < 8; j++) v[j] = (_Float16)cb_w2[(kt * 32 + kof + j) * 64 + c16];
            f1[(4 + kt) * 256 + t] = v;
        }
    } else if (bk == 1) {
        if (t >= 256) return;
        const int l = t & 63, w = t >> 6;
        const int kof = (l >> 4) * 8;
        const int c16 = w * 16 + (l & 15);
        {
            half8 v;
            #pragma unroll
            for (int j = 0; j < 8; j++) { int k = kof + j; v[j] = (k < 21) ? (_Float16)pe_w1[k * 64 + c16] : (_Float16)0.f; }
            f1[8 * 256 + t] = v;
        }
        #pragma unroll
        for (int kt = 0; kt < 2; kt++) {
            half8 v;
            #pragma unroll
            for (int j = 0; j < 8; j++) v[j] = (_Float16)pe_w2[(kt * 32 + kof + j) * 64 + c16];
            f1[(9 + kt) * 256 + t] = v;
        }
        #pragma unroll
        for (int ct = 0; ct < 2; ct++) {
            half8 v;
            #pragma unroll
            for (int j = 0; j < 8; j++) { int k = kof + j; v[j] = (k < 13) ? (_Float16)ee_w1[k * 32 + ct * 16 + (l & 15)] : (_Float16)0.f; }
            f1[(11 + ct) * 256 + t] = v;
        }
        {
            half8 v;
            #pragma unroll
            for (int j = 0; j < 8; j++) v[j] = (_Float16)ee_w2[(kof + j) * 16 + (l & 15)];
            f1[13 * 256 + t] = v;
        }
        float4 bb0, bb1;
        bb0.x = cb_b1[w * 32 + (l & 15)];
        bb0.y = cb_b1[w * 32 + 16 + (l & 15)];
        bb0.z = cb_b2[c16];
        bb0.w = pe_b1[c16];
        bb1.x = pe_b2[c16];
        bb1.y = ee_b1[l & 15];
        bb1.z = ee_b1[16 + (l & 15)];
        bb1.w = ee_b2[l & 15];
        b1v[t] = bb0;
        b1v[256 + t] = bb1;
    } else if (bk == 2 || bk == 3) {  // k2 fragments, ct = bk-2 (wave-local gate mapping)
        const int ct = bk - 2;
        const int l = t & 63, w = t >> 6;
        const int kof = (l >> 4) * 8;
        const int cc = ct * 16 + (l & 15);
        const int origc = (cc >> 3) * 64 + w * 8 + (cc & 7);
        #pragma unroll
        for (int kt = 0; kt < 4; kt++) {
            half8 v;
            #pragma unroll
            for (int j = 0; j < 8; j++) v[j] = (_Float16)ih_w[(kt * 32 + kof + j) * 256 + origc];
            f2[(ct * 4 + kt) * 512 + t] = v;
        }
        #pragma unroll
        for (int kt = 0; kt < 2; kt++) {
            half8 v;
            #pragma unroll
            for (int j = 0; j < 8; j++) v[j] = (_Float16)hh_w[(kt * 32 + kof + j) * 256 + origc];
            f2[(8 + ct * 2 + kt) * 512 + t] = v;
        }
        if (ct == 0) {
            const int cc1 = 16 + (l & 15);
            const int origc1 = (cc1 >> 3) * 64 + w * 8 + (cc1 & 7);
            float2 bb;
            bb.x = ih_b[origc] + hh_b[origc];
            bb.y = ih_b[origc1] + hh_b[origc1];
            b2v[t] = bb;
        }
    } else if (bk == 4) {
        if (t >= 256) return;
        const int l = t & 63;
        const int hc = l & 15;
        const int kof = (l >> 4) * 8;
        #pragma unroll
        for (int kt = 0; kt < 2; kt++) {
            half8 v;
            #pragma unroll
            for (int j = 0; j < 8; j++) {
                int k = kt * 32 + kof + j;
                float wv = 0.f;
                if (hc == 0) wv = th_w[k];
                else if (hc == 1) wv = an_w[k];
                else if (hc == 2) wv = sh_w[2 * k];
                else if (hc == 3) wv = sh_w[2 * k + 1];
                else if (hc == 4) wv = bo_w[2 * k];
                else if (hc == 5) wv = bo_w[2 * k + 1];
                v[j] = (_Float16)wv;
            }
            f4[kt * 256 + t] = v;
        }
        float bias = 0.f;
        if (hc == 0) bias = th_b[0];
        else if (hc == 1) bias = an_b[0];
        else if (hc == 2) bias = sh_b[0];
        else if (hc == 3) bias = sh_b[1];
        else if (hc == 4) bias = bo_b[0];
        else if (hc == 5) bias = bo_b[1];
        b4v[t] = bias;
    }
}

// ================= k1: all-MFMA encoders -> X[BS][128] f16 (39.9 KB LDS, R17 proven) =================
__global__ __launch_bounds__(256) void k1_encode(
    const float* __restrict__ self_obs, const float* __restrict__ tm_obs,
    const float* __restrict__ en_obs, const float* __restrict__ cp_obs,
    const int* __restrict__ role_ids, const float* __restrict__ role_emb,
    const char* __restrict__ Wp, unsigned int* __restrict__ Xg)
{
    __shared__ __align__(16) unsigned char s_raw[39936];
    __shared__ float eb[32];
    unsigned short* s_cin = (unsigned short*)(s_raw);
    unsigned short* s_pin = (unsigned short*)(s_raw + 9216);
    unsigned short* s_einh = (unsigned short*)(s_raw + 14336);
    unsigned short* s_emidh = (unsigned short*)(s_raw + 22016);
    unsigned short* s_lat16 = (unsigned short*)(s_raw + 29696);
    unsigned short* s_mid = (unsigned short*)(s_raw + 14336);
    unsigned short* s_xhalf = (unsigned short*)(s_raw + 31744);

    const int t = threadIdx.x;
    const int l = t & 63, w = t >> 6;
    const long long row0 = (long long)blockIdx.x * 64;

    for (int i = t; i < 7424; i += 256) ((unsigned int*)s_raw)[i] = 0;
    if (t < 32) eb[t] = role_emb[t];

    const half8* f1 = (const half8*)(Wp + WP_K1_FRAG);
    const float4* b1v = (const float4*)(Wp + WP_K1_BIAS);
    half8 bL1[2][2], bL2[4], bP1, bP2[2], bE1[2], bE2;
    bL1[0][0] = f1[0 * 256 + t]; bL1[0][1] = f1[1 * 256 + t];
    bL1[1][0] = f1[2 * 256 + t]; bL1[1][1] = f1[3 * 256 + t];
    #pragma unroll
    for (int kt = 0; kt < 4; kt++) bL2[kt] = f1[(4 + kt) * 256 + t];
    bP1 = f1[8 * 256 + t];
    bP2[0] = f1[9 * 256 + t]; bP2[1] = f1[10 * 256 + t];
    bE1[0] = f1[11 * 256 + t]; bE1[1] = f1[12 * 256 + t];
    bE2 = f1[13 * 256 + t];
    float4 bb0 = b1v[t], bb1 = b1v[256 + t];
    float bsL1[2] = {bb0.x, bb0.y};
    float bsL2 = bb0.z, bsP1 = bb0.w, bsP2 = bb1.x;
    float bsE1[2] = {bb1.y, bb1.z};
    float bsE2 = bb1.w;
    __syncthreads();

    const int arow = l & 15;
    const int crow0 = (l >> 4) * 4;
    const int kof = (l >> 4) * 8;
    const int c16 = w * 16 + (l & 15);

    for (int idx = t; idx < 960; idx += 256) {
        int r = idx / 15, k = idx - r * 15;
        unsigned short hv = f2h16(self_obs[row0 * 15 + idx]);
        s_cin[r * 72 + k] = hv;
        s_pin[r * 40 + k] = hv;
    }
    for (int idx = t; idx < 384; idx += 256) {
        int r = idx / 6, k = idx - r * 6;
        s_pin[r * 40 + 15 + k] = f2h16(cp_obs[row0 * 6 + idx]);
    }

    #pragma unroll 1
    for (int p = 0; p < 2; p++) {
        for (int idx = t; idx < 416; idx += 256) {
            int r = idx / 13, k = idx - r * 13;
            s_einh[(3 * r) * 40 + k] = f2h16(tm_obs[(row0 + 32 * p) * 13 + idx]);
        }
        for (int idx = t; idx < 832; idx += 256) {
            int r = idx / 26, rem = idx - r * 26;
            int src = rem / 13, k = rem - src * 13;
            s_einh[(3 * r + 1 + src) * 40 + k] = f2h16(en_obs[(row0 + 32 * p) * 26 + idx]);
        }
        __syncthreads();
        #pragma unroll
        for (int i = 0; i < 2; i++) {
            int rt = w + i * 4;
            if (rt < 6) {
                half8 a = *(const half8*)(s_einh + (rt * 16 + arow) * 40 + kof);
                #pragma unroll
                for (int ct = 0; ct < 2; ct++) {
                    floatx4 acc = {bsE1[ct], bsE1[ct], bsE1[ct], bsE1[ct]};
                    acc = __builtin_amdgcn_mfma_f32_16x16x32_f16(a, bE1[ct], acc, 0, 0, 0);
                    #pragma unroll
                    for (int rr = 0; rr < 4; rr++)
                        s_emidh[(rt * 16 + crow0 + rr) * 40 + ct * 16 + (l & 15)] = f2h16(fmaxf(acc[rr], 0.f));
                }
            }
        }
        __syncthreads();
        #pragma unroll
        for (int i = 0; i < 2; i++) {
            int rt = w + i * 4;
            if (rt < 6) {
                half8 a = *(const half8*)(s_emidh + (rt * 16 + arow) * 40 + kof);
                floatx4 acc = {bsE2, bsE2, bsE2, bsE2};
                acc = __builtin_amdgcn_mfma_f32_16x16x32_f16(a, bE2, acc, 0, 0, 0);
                #pragma unroll
                for (int rr = 0; rr < 4; rr++)
                    s_lat16[(96 * p + rt * 16 + crow0 + rr) * 17 + (l & 15)] = f2h16(acc[rr]);
            }
        }
        __syncthreads();
    }

    {
        const int r = t >> 2, q = t & 3;
        int rid = role_ids[row0 + r];
        #pragma unroll
        for (int j = 0; j < 4; j++) {
            int o = q * 4 + j;
            unsigned short tm16 = s_lat16[(3 * r) * 17 + o];
            float e1f = h16f(s_lat16[(3 * r + 1) * 17 + o]);
            float e2f = h16f(s_lat16[(3 * r + 2) * 17 + o]);
            s_cin[r * 72 + 15 + o] = tm16;
            s_cin[r * 72 + 31 + o] = f2h16(fmaxf(e1f, e2f));
            s_cin[r * 72 + 47 + o] = f2h16(eb[rid * 16 + o]);
        }
    }
    __syncthreads();

    #pragma unroll 1
    for (int rt = 0; rt < 4; rt++) {
        half8 a0 = *(const half8*)(s_cin + (rt * 16 + arow) * 72 + kof);
        half8 a1 = *(const half8*)(s_cin + (rt * 16 + arow) * 72 + 32 + kof);
        #pragma unroll
        for (int ct = 0; ct < 2; ct++) {
            floatx4 acc = {bsL1[ct], bsL1[ct], bsL1[ct], bsL1[ct]};
            acc = __builtin_amdgcn_mfma_f32_16x16x32_f16(a0, bL1[ct][0], acc, 0, 0, 0);
            acc = __builtin_amdgcn_mfma_f32_16x16x32_f16(a1, bL1[ct][1], acc, 0, 0, 0);
            int col = w * 32 + ct * 16 + (l & 15);
            #pragma unroll
            for (int rr = 0; rr < 4; rr++)
                s_mid[(rt * 16 + crow0 + rr) * 136 + col] = f2h16(fmaxf(acc[rr], 0.f));
        }
    }
    __syncthreads();
    #pragma unroll 1
    for (int rt = 0; rt < 4; rt++) {
        floatx4 acc = {bsL2, bsL2, bsL2, bsL2};
        #pragma unroll
        for (int kt = 0; kt < 4; kt++) {
            half8 a = *(const half8*)(s_mid + (rt * 16 + arow) * 136 + kt * 32 + kof);
            acc = __builtin_amdgcn_mfma_f32_16x16x32_f16(a, bL2[kt], acc, 0, 0, 0);
        }
        #pragma unroll
        for (int rr = 0; rr < 4; rr++)
            s_xhalf[(rt * 16 + crow0 + rr) * 64 + c16] = f2h16(fmaxf(acc[rr], 0.f));
    }
    __syncthreads();
    #pragma unroll
    for (int rep = 0; rep < 2; rep++) {
        int idx = rep * 256 + t;
        int r = idx >> 3, q2 = idx & 7;
        ((uint4*)(Xg + (row0 + r) * 64 + 32))[q2] = ((const uint4*)s_xhalf)[r * 8 + q2];
    }
    #pragma unroll 1
    for (int rt = 0; rt < 4; rt++) {
        half8 a = *(const half8*)(s_pin + (rt * 16 + arow) * 40 + kof);
        floatx4 acc = {bsP1, bsP1, bsP1, bsP1};
        acc = __builtin_amdgcn_mfma_f32_16x16x32_f16(a, bP1, acc, 0, 0, 0);
        #pragma unroll
        for (int rr = 0; rr < 4; rr++)
            s_mid[(rt * 16 + crow0 + rr) * 136 + c16] = f2h16(fmaxf(acc[rr], 0.f));
    }
    __syncthreads();
    #pragma unroll 1
    for (int rt = 0; rt < 4; rt++) {
        floatx4 acc = {bsP2, bsP2, bsP2, bsP2};
        #pragma unroll
        for (int kt = 0; kt < 2; kt++) {
            half8 a = *(const half8*)(s_mid + (rt * 16 + arow) * 136 + kt * 32 + kof);
            acc = __builtin_amdgcn_mfma_f32_16x16x32_f16(a, bP2[kt], acc, 0, 0, 0);
        }
        #pragma unroll
        for (int rr = 0; rr < 4; rr++)
            s_xhalf[(rt * 16 + crow0 + rr) * 64 + c16] = f2h16(fmaxf(acc[rr], 0.f));
    }
    __syncthreads();
    #pragma unroll
    for (int rep = 0; rep < 2; rep++) {
        int idx = rep * 256 + t;
        int r = idx >> 3, q2 = idx & 7;
        ((uint4*)(Xg + (row0 + r) * 64))[q2] = ((const uint4*)s_xhalf)[r * 8 + q2];
    }
}

// ================= k2: MFMA LSTM — step-pair A-frames, transposed gate scratch (R18 proven) =================
__global__ __launch_bounds__(512) void k2_lstm(
    const char* __restrict__ Wp,
    const unsigned int* __restrict__ Xg, unsigned short* __restrict__ hseq,
    float* __restrict__ out)
{
    __shared__ __align__(16) unsigned short s_x[2][2][16][136];  // [buf][step-pair][16 rows: 0-7=even step, 8-15=odd][136]
    __shared__ __align__(16) unsigned short s_h[16][72];         // h duplicated in rows 0-7 and 8-15
    __shared__ __align__(16) float s_gwT[8][8][32];              // [wave][row][ul*4+gate]

    const int t = threadIdx.x;
    const int bb = blockIdx.x;
    const int l = t & 63;
    const int w = t >> 6;

    {
        unsigned int* z = (unsigned int*)&s_x[0][0][0][0];
        for (int i = t; i < 4352; i += 512) z[i] = 0;
        unsigned int* z2 = (unsigned int*)&s_h[0][0];
        for (int i = t; i < 576; i += 512) z2[i] = 0;
    }

    const int kof = (l >> 4) * 8;
    const half8* f2 = (const half8*)(Wp + WP_K2_FRAG);
    const float2* b2v = (const float2*)(Wp + WP_K2_BIAS);
    half8 bx[2][4], bh[2][2];
    #pragma unroll
    for (int ct = 0; ct < 2; ct++) {
        #pragma unroll
        for (int kt = 0; kt < 4; kt++) bx[ct][kt] = f2[(ct * 4 + kt) * 512 + t];
        #pragma unroll
        for (int kt = 0; kt < 2; kt++) bh[ct][kt] = f2[(8 + ct * 2 + kt) * 512 + t];
    }
    float2 bbv = b2v[t];
    float biasv[2] = {bbv.x, bbv.y};

    // loader: thread -> (step-in-chunk, row, 16B segment); dst row = 8*(step&1)+r, pair = step>>1
    const int step_ld = t >> 7;          // 0..3
    const int r_ld = (t >> 4) & 7;       // 0..7
    const int seg = t & 15;              // 0..15
    const int dst_pair = step_ld >> 1;
    const int dst_row = 8 * (step_ld & 1) + r_ld;
    const long long gb0 = (long long)bb * 8;
    uint4 p;

    __syncthreads();
    {
        const unsigned int* src = Xg + ((gb0 + r_ld) * Sn + step_ld) * 64 + seg * 4;
        p = *(const uint4*)src;
        *(uint4*)((unsigned int*)&s_x[0][dst_pair][dst_row][0] + seg * 4) = p;
    }
    __syncthreads();
    {
        const unsigned int* src = Xg + ((gb0 + r_ld) * Sn + (4 + step_ld)) * 64 + seg * 4;
        p = *(const uint4*)src;
    }

    const int arow = l & 15;
    const int urow = l >> 3;      // consumer row 0..7
    const int ul = l & 7;         // consumer unit-local (global unit = 8w + ul)
    const int pside = (l >> 5) & 1;       // producer side: 0 = lanes 0-31 (even steps), 1 = lanes 32-63 (odd)
    const int cc0 = l & 15;
    const int rbase = ((l >> 4) & 1) * 4; // producer batch-row base within its side
    float cst = 0.f, hst = 0.f;

    #pragma unroll 1
    for (int c = 0; c < 64; c++) {
        const int buf = c & 1;
        // ---- batched x-part: step-pair frames (16 MFMAs, 8 ds_reads per chunk) ----
        floatx4 wxa[2][2];
        #pragma unroll
        for (int sl2 = 0; sl2 < 2; sl2++) {
            half8 xa0 = *(const half8*)&s_x[buf][sl2][arow][kof];
            half8 xa1 = *(const half8*)&s_x[buf][sl2][arow][32 + kof];
            half8 xa2 = *(const half8*)&s_x[buf][sl2][arow][64 + kof];
            half8 xa3 = *(const half8*)&s_x[buf][sl2][arow][96 + kof];
            floatx4 a0 = {biasv[0], biasv[0], biasv[0], biasv[0]};
            floatx4 a1 = {biasv[1], biasv[1], biasv[1], biasv[1]};
            a0 = __builtin_amdgcn_mfma_f32_16x16x32_f16(xa0, bx[0][0], a0, 0, 0, 0);
            a1 = __builtin_amdgcn_mfma_f32_16x16x32_f16(xa0, bx[1][0], a1, 0, 0, 0);
            a0 = __builtin_amdgcn_mfma_f32_16x16x32_f16(xa1, bx[0][1], a0, 0, 0, 0);
            a1 = __builtin_amdgcn_mfma_f32_16x16x32_f16(xa1, bx[1][1], a1, 0, 0, 0);
            a0 = __builtin_amdgcn_mfma_f32_16x16x32_f16(xa2, bx[0][2], a0, 0, 0, 0);
            a1 = __builtin_amdgcn_mfma_f32_16x16x32_f16(xa2, bx[1][2], a1, 0, 0, 0);
            a0 = __builtin_amdgcn_mfma_f32_16x16x32_f16(xa3, bx[0][3], a0, 0, 0, 0);
            a1 = __builtin_amdgcn_mfma_f32_16x16x32_f16(xa3, bx[1][3], a1, 0, 0, 0);
            wxa[sl2][0] = a0;
            wxa[sl2][1] = a1;
        }
        // ---- serial sub-loop ----
        #pragma unroll
        for (int sl = 0; sl < 4; sl++) {
            const int sl2 = sl >> 1;
            const int odd = sl & 1;
            half8 hA0 = *(const half8*)&s_h[arow][kof];
            half8 hA1 = *(const half8*)&s_h[arow][32 + kof];
            floatx4 acc0 = wxa[sl2][0];
            floatx4 acc1 = wxa[sl2][1];
            acc0 = __builtin_amdgcn_mfma_f32_16x16x32_f16(hA0, bh[0][0], acc0, 0, 0, 0);
            acc1 = __builtin_amdgcn_mfma_f32_16x16x32_f16(hA0, bh[1][0], acc1, 0, 0, 0);
            acc0 = __builtin_amdgcn_mfma_f32_16x16x32_f16(hA1, bh[0][1], acc0, 0, 0, 0);
            acc1 = __builtin_amdgcn_mfma_f32_16x16x32_f16(hA1, bh[1][1], acc1, 0, 0, 0);
            // producer side for this step writes its valid C-rows (transposed layout)
            if (pside == odd) {
                const int ga = cc0 >> 3;     // 0 or 1
                const int up = cc0 & 7;
                #pragma unroll
                for (int rr = 0; rr < 4; rr++) {
                    s_gwT[w][rbase + rr][up * 4 + ga] = acc0[rr];
                    s_gwT[w][rbase + rr][up * 4 + 2 + ga] = acc1[rr];
                }
            }
            __builtin_amdgcn_wave_barrier();
            {
                const float4 gv = *(const float4*)&s_gwT[w][urow][ul * 4];  // i,f,g,o
                float i_ = sigmoidf_(gv.x), f_ = sigmoidf_(gv.y);
                float g_ = tanhf_(gv.z), o_ = sigmoidf_(gv.w);
                cst = f_ * cst + i_ * g_;
                hst = o_ * tanhf_(cst);
                unsigned short h16 = f2h16(hst);
                s_h[urow][w * 8 + ul] = h16;
                s_h[8 + urow][w * 8 + ul] = h16;
                hseq[((gb0 + urow) * Sn + (c * 4 + sl)) * 64 + w * 8 + ul] = h16;
            }
            if (sl == 3 && c < 63)
                *(uint4*)((unsigned int*)&s_x[buf ^ 1][dst_pair][dst_row][0] + seg * 4) = p;
            __syncthreads();
        }
        if (c < 62) {
            const unsigned int* src = Xg + ((gb0 + r_ld) * Sn + ((c + 2) * 4 + step_ld)) * 64 + seg * 4;
            p = *(const uint4*)src;
        }
    }
    float* hn = out + 8 * BSn;
    float* cn = hn + (long long)Bn * 64;
    hn[(gb0 + urow) * 64 + w * 8 + ul] = hst;
    cn[(gb0 + urow) * 64 + w * 8 + ul] = cst;
}

// ================= k4: heads (MFMA over hseq) + std fill =================
__global__ __launch_bounds__(256) void k4_heads(
    const unsigned short* __restrict__ hseq, const char* __restrict__ Wp,
    const float* __restrict__ logstd, float* __restrict__ out)
{
    const int t = threadIdx.x, l = t & 63, w = t >> 6;
    const long long row0 = (long long)blockIdx.x * 64 + w * 16;
    const int hc = l & 15;
    const int kof = (l >> 4) * 8;
    const half8* f4 = (const half8*)(Wp + WP_K4_FRAG);
    half8 bhd0 = f4[t], bhd1 = f4[256 + t];
    float bias = ((const float*)(Wp + WP_K4_BIAS))[t];
    const unsigned short* hp = hseq + (row0 + (l & 15)) * 64;
    half8 a0 = *(const half8*)(hp + kof);
    half8 a1 = *(const half8*)(hp + 32 + kof);
    floatx4 acc = {bias, bias, bias, bias};
    acc = __builtin_amdgcn_mfma_f32_16x16x32_f16(a0, bhd0, acc, 0, 0, 0);
    acc = __builtin_amdgcn_mfma_f32_16x16x32_f16(a1, bhd1, acc, 0, 0, 0);
    float s0 = fmaxf(__expf(logstd[0]), 0.05f);
    float s1 = fmaxf(__expf(logstd[1]), 0.05f);
    #pragma unroll
    for (int rr = 0; rr < 4; rr++) {
        long long row = row0 + (l >> 4) * 4 + rr;
        float v = acc[rr];
        if (hc == 0)      out[row] = sigmoidf_(v);
        else if (hc == 1) out[BSn + row] = tanhf_(v);
        else if (hc == 2) out[4 * BSn + 2 * row] = v;
        else if (hc == 3) out[4 * BSn + 2 * row + 1] = v;
        else if (hc == 4) out[6 * BSn + 2 * row] = v;
        else if (hc == 5) out[6 * BSn + 2 * row + 1] = v;
        else if (hc == 6) out[2 * BSn + 2 * row] = s0;
        else if (hc == 7) out[2 * BSn + 2 * row + 1] = s1;
    }
}

// ================= fallback: monolithic (R3 structure, proven @1454us) =================
enum {
    O_PE1 = 0, O_PE2 = 768, O_EE1 = 2816, O_EE2 = 3072,
    O_CB1 = 3328, O_CB2 = 7424, O_BIAS = 11520
};
__global__ __launch_bounds__(256)
void k_fallback(
    const float* __restrict__ self_obs, const float* __restrict__ tm_obs,
    const float* __restrict__ en_obs, const float* __restrict__ cp_obs,
    const int* __restrict__ role_ids,
    const float* __restrict__ pe_w1, const float* __restrict__ pe_b1,
    const float* __restrict__ pe_w2, const float* __restrict__ pe_b2,
    const float* __restrict__ role_emb,
    const float* __restrict__ ee_w1, const float* __restrict__ ee_b1,
    const float* __restrict__ ee_w2, const float* __restrict__ ee_b2,
    const float* __restrict__ cb_w1, const float* __restrict__ cb_b1,
    const float* __restrict__ cb_w2, const float* __restrict__ cb_b2,
    const float* __restrict__ ih_w, const float* __restrict__ ih_b,
    const float* __restrict__ hh_w, const float* __restrict__ hh_b,
    const float* __restrict__ th_w, const float* __restrict__ th_b,
    const float* __restrict__ an_w, const float* __restrict__ an_b,
    const float* __restrict__ sh_w, const float* __restrict__ sh_b,
    const float* __restrict__ bo_w, const float* __restrict__ bo_b,
    const float* __restrict__ logstd, float* __restrict__ out)
{
    __shared__ __align__(16) unsigned int s_tile[Sn * 64];
    __shared__ __align__(16) unsigned int s_h32[32];
    __shared__ float s_g[192];
    __shared__ unsigned int s_hw[192];
    __shared__ float s_hb[8];

    const int t = threadIdx.x;
    const int b = blockIdx.x;

    for (int i = t; i < 768; i += 256) {
        int o = i / 12, m = i % 12, k0 = 2 * m, k1 = k0 + 1;
        float a = (k0 < 21) ? pe_w1[k0 * 64 + o] : 0.f;
        float c = (k1 < 21) ? pe_w1[k1 * 64 + o] : 0.f;
        s_tile[O_PE1 + i] = packh2(a, c);
    }
    for (int i = t; i < 2048; i += 256) {
        int o = i >> 5, m = i & 31;
        s_tile[O_PE2 + i] = packh2(pe_w2[(2 * m) * 64 + o], pe_w2[(2 * m + 1) * 64 + o]);
    }
    {
        int i = t;
        int o = i >> 3, m = i & 7, k0 = 2 * m, k1 = k0 + 1;
        float a = (k0 < 13) ? ee_w1[k0 * 32 + o] : 0.f;
        float c = (k1 < 13) ? ee_w1[k1 * 32 + o] : 0.f;
        s_tile[O_EE1 + i] = packh2(a, c);
    }
    {
        int i = t;
        int o = i >> 4, m = i & 15;
        s_tile[O_EE2 + i] = packh2(ee_w2[(2 * m) * 16 + o], ee_w2[(2 * m + 1) * 16 + o]);
    }
    for (int i = t; i < 4096; i += 256) {
        int o = i >> 5, m = i & 31, k0 = 2 * m, k1 = k0 + 1;
        float a = (k0 < 63) ? cb_w1[k0 * 128 + o] : 0.f;
        float c = (k1 < 63) ? cb_w1[k1 * 128 + o] : 0.f;
        s_tile[O_CB1 + i] = packh2(a, c);
    }
    for (int i = t; i < 4096; i += 256) {
        int o = i >> 6, m = i & 63;
        s_tile[O_CB2 + i] = packh2(cb_w2[(2 * m) * 64 + o], cb_w2[(2 * m + 1) * 64 + o]);
    }
    float* bias = (float*)(s_tile + O_BIAS);
    if (t < 64) bias[t] = pe_b1[t];
    if (t < 64) bias[64 + t] = pe_b2[t];
    if (t < 32) bias[128 + t] = ee_b1[t];
    if (t < 16) bias[160 + t] = ee_b2[t];
    if (t < 128) bias[176 + t] = cb_b1[t];
    if (t < 64) bias[304 + t] = cb_b2[t];
    if (t < 32) bias[368 + t] = role_emb[t];
    if (t < 32)        s_hw[t]        = packh2(th_w[2 * t], th_w[2 * t + 1]);
    else if (t < 64)  { int m = t - 32;  s_hw[32 + m]  = packh2(an_w[2 * m], an_w[2 * m + 1]); }
    else if (t < 96)  { int m = t - 64;  s_hw[64 + m]  = packh2(sh_w[4 * m], sh_w[4 * m + 2]); }
    else if (t < 128) { int m = t - 96;  s_hw[96 + m]  = packh2(sh_w[4 * m + 1], sh_w[4 * m + 3]); }
    else if (t < 160) { int m = t - 128; s_hw[128 + m] = packh2(bo_w[4 * m], bo_w[4 * m + 2]); }
    else if (t < 192) { int m = t - 160; s_hw[160 + m] = packh2(bo_w[4 * m + 1], bo_w[4 * m + 3]); }
    if (t == 0) {
        s_hb[0] = th_b[0]; s_hb[1] = an_b[0];
        s_hb[2] = sh_b[0]; s_hb[3] = sh_b[1];
        s_hb[4] = bo_b[0]; s_hb[5] = bo_b[1];
        s_hb[6] = fmaxf(__expf(logstd[0]), 0.05f);
        s_hb[7] = fmaxf(__expf(logstd[1]), 0.05f);
    }
    if (t < 32) s_h32[t] = 0u;
    __syncthreads();

    {
        const long long row = (long long)b * Sn + t;
        float lat[32];
        #pragma unroll 1
        for (int src = 0; src < 3; src++) {
            const float* xp = (src == 0) ? (tm_obs + row * 13) : (en_obs + row * 26 + (src - 1) * 13);
            unsigned int xpr[8];
            #pragma unroll
            for (int m = 0; m < 8; m++) {
                int k0 = 2 * m, k1 = k0 + 1;
                xpr[m] = packh2((k0 < 13) ? xp[k0] : 0.f, (k1 < 13) ? xp[k1] : 0.f);
            }
            unsigned int e1[16];
            #pragma unroll
            for (int o2 = 0; o2 < 16; o2++) {
                float a0 = bias[128 + 2 * o2], a1 = bias[128 + 2 * o2 + 1];
                const unsigned int* w0 = s_tile + O_EE1 + (2 * o2) * 8;
                #pragma unroll
                for (int m = 0; m < 8; m++) { a0 = dot2(xpr[m], w0[m], a0); a1 = dot2(xpr[m], w0[8 + m], a1); }
                e1[o2] = packh2(fmaxf(a0, 0.f), fmaxf(a1, 0.f));
            }
            #pragma unroll
            for (int o = 0; o < 16; o++) {
                float a0 = bias[160 + o];
                const unsigned int* w0 = s_tile + O_EE2 + o * 16;
                #pragma unroll
                for (int m = 0; m < 16; m++) a0 = dot2(e1[m], w0[m], a0);
                if (src == 0) lat[o] = a0;
                else if (src == 1) lat[16 + o] = a0;
                else lat[16 + o] = fmaxf(lat[16 + o], a0);
            }
        }
        unsigned int cpp[32];
        {
            const float* sp = self_obs + row * 15;
            const int rid = role_ids[row];
            const float* rvec = bias + 368 + rid * 16;
            #pragma unroll
            for (int m = 0; m < 32; m++) {
                int k0 = 2 * m, k1 = k0 + 1;
                float a = (k0 < 15) ? sp[k0] : (k0 < 31) ? lat[k0 - 15] : (k0 < 47) ? lat[16 + k0 - 31] : rvec[k0 - 47];
                float c = (k1 < 15) ? sp[k1] : (k1 < 31) ? lat[k1 - 15] : (k1 < 47) ? lat[16 + k1 - 31]
                                                                       : (k1 < 63) ? rvec[k1 - 47] : 0.f;
                cpp[m] = packh2(a, c);
            }
        }
        unsigned int c1[64];
        #pragma unroll
        for (int o2 = 0; o2 < 64; o2++) {
            float a0 = bias[176 + 2 * o2], a1 = bias[176 + 2 * o2 + 1];
            const unsigned int* w0 = s_tile + O_CB1 + (2 * o2) * 32;
            #pragma unroll
            for (int m = 0; m < 32; m++) { a0 = dot2(cpp[m], w0[m], a0); a1 = dot2(cpp[m], w0[32 + m], a1); }
            c1[o2] = packh2(fmaxf(a0, 0.f), fmaxf(a1, 0.f));
        }
        unsigned int resc[32];
        #pragma unroll
        for (int o2 = 0; o2 < 32; o2++) {
            float a0 = bias[304 + 2 * o2], a1 = bias[304 + 2 * o2 + 1];
            const unsigned int* w0 = s_tile + O_CB2 + (2 * o2) * 64;
            #pragma unroll
            for (int m = 0; m < 64; m++) { a0 = dot2(c1[m], w0[m], a0); a1 = dot2(c1[m], w0[64 + m], a1); }
            resc[o2] = packh2(fmaxf(a0, 0.f), fmaxf(a1, 0.f));
        }
        unsigned int inp[12];
        {
            const float* sp = self_obs + row * 15;
            const float* cp = cp_obs + row * 6;
            #pragma unroll
            for (int m = 0; m < 12; m++) {
                int k0 = 2 * m, k1 = k0 + 1;
                float a = (k0 < 15) ? sp[k0] : ((k0 < 21) ? cp[k0 - 15] : 0.f);
                float c = (k1 < 15) ? sp[k1] : ((k1 < 21) ? cp[k1 - 15] : 0.f);
                inp[m] = packh2(a, c);
            }
        }
        unsigned int r1p[32];
        #pragma unroll
        for (int o2 = 0; o2 < 32; o2++) {
            float a0 = bias[2 * o2], a1 = bias[2 * o2 + 1];
            const unsigned int* w0 = s_tile + O_PE1 + (2 * o2) * 12;
            #pragma unroll
            for (int m = 0; m < 12; m++) { a0 = dot2(inp[m], w0[m], a0); a1 = dot2(inp[m], w0[12 + m], a1); }
            r1p[o2] = packh2(fmaxf(a0, 0.f), fmaxf(a1, 0.f));
        }
        unsigned int resp[32];
        #pragma unroll
        for (int o2 = 0; o2 < 32; o2++) {
            float a0 = bias[64 + 2 * o2], a1 = bias[64 + 2 * o2 + 1];
            const unsigned int* w0 = s_tile + O_PE2 + (2 * o2) * 32;
            #pragma unroll
            for (int m = 0; m < 32; m++) { a0 = dot2(r1p[m], w0[m], a0); a1 = dot2(r1p[m], w0[32 + m], a1); }
            resp[o2] = packh2(fmaxf(a0, 0.f), fmaxf(a1, 0.f));
        }
        __syncthreads();
        uint4* rt4 = reinterpret_cast<uint4*>(s_tile + t * 64);
        #pragma unroll
        for (int q = 0; q < 8; q++)
            rt4[q] = make_uint4(resp[4 * q], resp[4 * q + 1], resp[4 * q + 2], resp[4 * q + 3]);
        #pragma unroll
        for (int q = 0; q < 8; q++)
            rt4[8 + q] = make_uint4(resc[4 * q], resc[4 * q + 1], resc[4 * q + 2], resc[4 * q + 3]);
    }

    unsigned int wih[64], whh[32];
    #pragma unroll
    for (int m = 0; m < 64; m++) wih[m] = packh2(ih_w[(2 * m) * 256 + t], ih_w[(2 * m + 1) * 256 + t]);
    #pragma unroll
    for (int m = 0; m < 32; m++) whh[m] = packh2(hh_w[(2 * m) * 256 + t], hh_w[(2 * m + 1) * 256 + t]);
    const float bias_t = ih_b[t] + hh_b[t];
    __syncthreads();

    const int grp = t >> 6;
    const int u = t & 63;
    float c = 0.f, h = 0.f, i_act = 0.f;
    #pragma unroll 1
    for (int s = 0; s < Sn; s++) {
        float acc = bias_t;
        const uint4* rq = reinterpret_cast<const uint4*>(s_tile + s * 64);
        #pragma unroll
        for (int q = 0; q < 16; q++) {
            uint4 rv = rq[q];
            acc = dot2(rv.x, wih[4 * q + 0], acc);
            acc = dot2(rv.y, wih[4 * q + 1], acc);
            acc = dot2(rv.z, wih[4 * q + 2], acc);
            acc = dot2(rv.w, wih[4 * q + 3], acc);
        }
        const uint4* hq = reinterpret_cast<const uint4*>(s_h32);
        #pragma unroll
        for (int q = 0; q < 8; q++) {
            uint4 hvv = hq[q];
            acc = dot2(hvv.x, whh[4 * q + 0], acc);
            acc = dot2(hvv.y, whh[4 * q + 1], acc);
            acc = dot2(hvv.z, whh[4 * q + 2], acc);
            acc = dot2(hvv.w, whh[4 * q + 3], acc);
        }
        float act = (grp == 2) ? tanhf_(acc) : sigmoidf_(acc);
        if (grp == 0) i_act = act; else s_g[t - 64] = act;
        __syncthreads();
        if (t < 64) {
            float f_ = s_g[u], g_ = s_g[64 + u], o_ = s_g[128 + u];
            c = f_ * c + i_act * g_;
            h = o_ * tanhf_(c);
            float hnext = __shfl_down(h, 1);
            if ((u & 1) == 0) {
                unsigned int hp = packh2(h, hnext);
                s_h32[u >> 1] = hp;
                s_tile[s * 64 + (((u >> 1) + s) & 31)] = hp;
            }
        }
        __syncthreads();
    }
    {
        const int w = t >> 6, lq = t & 63;
        const int m0 = (lq & 7) * 4;
        const int j0 = lq & 7;
        #pragma unroll 1
        for (int p = 0; p < 8; p++) {
            int s = w * 64 + p * 8 + (lq >> 3);
            float ath = 0.f, aan = 0.f, as0 = 0.f, as1 = 0.f, ab0 = 0.f, ab1 = 0.f;
            #pragma unroll
            for (int j = 0; j < 4; j++) {
                int m = m0 + j;
                unsigned int hvv = s_tile[s * 64 + ((m + s) & 31)];
                ath = dot2(hvv, s_hw[m], ath);
                aan = dot2(hvv, s_hw[32 + m], aan);
                as0 = dot2(hvv, s_hw[64 + m], as0);
                as1 = dot2(hvv, s_hw[96 + m], as1);
                ab0 = dot2(hvv, s_hw[128 + m], ab0);
                ab1 = dot2(hvv, s_hw[160 + m], ab1);
            }
            #pragma unroll
            for (int d = 1; d < 8; d <<= 1) {
                ath += __shfl_xor(ath, d); aan += __shfl_xor(aan, d);
                as0 += __shfl_xor(as0, d); as1 += __shfl_xor(as1, d);
                ab0 += __shfl_xor(ab0, d); ab1 += __shfl_xor(ab1, d);
            }
            long long row = (long long)b * Sn + s;
            if (j0 == 0)      out[row] = sigmoidf_(ath + s_hb[0]);
            else if (j0 == 1) out[BSn + row] = tanhf_(aan + s_hb[1]);
            else if (j0 == 2) out[2 * BSn + 2 * row] = s_hb[6];
            else if (j0 == 3) out[2 * BSn + 2 * row + 1] = s_hb[7];
            else if (j0 == 4) out[4 * BSn + 2 * row] = as0 + s_hb[2];
            else if (j0 == 5) out[4 * BSn + 2 * row + 1] = as1 + s_hb[3];
            else if (j0 == 6) out[6 * BSn + 2 * row] = ab0 + s_hb[4];
            else              out[6 * BSn + 2 * row + 1] = ab1 + s_hb[5];
        }
    }
    if (t < 64) {
        float* hn = out + 8 * BSn;
        float* cn = hn + (long long)Bn * 64;
        hn[(long long)b * 64 + u] = h;
        cn[(long long)b * 64 + u] = c;
    }
}

// ================= host =================
extern "C" void kernel_launch(void* const* d_in, const int* in_sizes, int n_in,
                              void* d_out, int out_size, void* d_ws, size_t ws_size,
                              hipStream_t stream)
{
    (void)in_sizes; (void)n_in; (void)out_size;
    float* out = (float*)d_out;
    const size_t X_BYTES = (size_t)BSn * 64 * 4;  // 134 MB (f16 pairs as u32)
    const size_t H_BYTES = (size_t)BSn * 64 * 2;  // 67 MB hseq f16

    if (d_ws != nullptr && ws_size >= X_BYTES + H_BYTES + WP_TOTAL) {
        unsigned int* Xg = (unsigned int*)d_ws;
        unsigned short* hseq = (unsigned short*)((char*)d_ws + X_BYTES);
        char* Wp = (char*)d_ws + X_BYTES + H_BYTES;
        k0_pack<<<6, 512, 0, stream>>>(
            (const float*)d_in[5], (const float*)d_in[6], (const float*)d_in[7], (const float*)d_in[8],
            (const float*)d_in[10], (const float*)d_in[11], (const float*)d_in[12], (const float*)d_in[13],
            (const float*)d_in[14], (const float*)d_in[15], (const float*)d_in[16], (const float*)d_in[17],
            (const float*)d_in[18], (const float*)d_in[19], (const float*)d_in[20], (const float*)d_in[21],
            (const float*)d_in[22], (const float*)d_in[23], (const float*)d_in[24], (const float*)d_in[25],
            (const float*)d_in[26], (const float*)d_in[27], (const float*)d_in[28], (const float*)d_in[29],
            Wp);
        k1_encode<<<(int)(BSn / 64), 256, 0, stream>>>(
            (const float*)d_in[0], (const float*)d_in[1], (const float*)d_in[2],
            (const float*)d_in[3], (const int*)d_in[4], (const float*)d_in[9],
            Wp, Xg);
        k2_lstm<<<Bn / 8, 512, 0, stream>>>(Wp, Xg, hseq, out);
        k4_heads<<<(int)(BSn / 64), 256, 0, stream>>>(hseq, Wp, (const float*)d_in[30], out);
    } else {
        k_fallback<<<Bn, 256, 0, stream>>>(
            (const float*)d_in[0], (const float*)d_in[1], (const float*)d_in[2],
            (const float*)d_in[3], (const int*)d_in[4],
            (const float*)d_in[5], (const float*)d_in[6], (const float*)d_in[7], (const float*)d_in[8],
            (const float*)d_in[9],
            (const float*)d_in[10], (const float*)d_in[11], (const float*)d_in[12], (const float*)d_in[13],
            (const float*)d_in[14], (const float*)d_in[15], (const float*)d_in[16], (const float*)d_in[17],
            (const float*)d_in[18], (const float*)d_in[19], (const float*)d_in[20], (const float*)d_in[21],
            (const float*)d_in[22], (const float*)d_in[23], (const float*)d_in[24], (const float*)d_in[25],
            (const float*)d_in[26], (const float*)d_in[27], (const float*)d_in[28], (const float*)d_in[29],
            (const float*)d_in[30], out);
    }
}

// Round 21
// 357.325 us; speedup vs baseline: 1.0114x; 1.0114x over previous
//
#include <hip/hip_runtime.h>
#include <hip/hip_fp16.h>

#define DEVINL __device__ __forceinline__

static constexpr int Bn = 2048;
static constexpr int Sn = 256;
static constexpr long long BSn = (long long)Bn * Sn;  // 524288

typedef _Float16 h2v __attribute__((ext_vector_type(2)));
typedef _Float16 half8 __attribute__((ext_vector_type(8)));
typedef float floatx4 __attribute__((ext_vector_type(4)));

DEVINL float dot2(unsigned int a, unsigned int b, float c) {
#if __has_builtin(__builtin_amdgcn_fdot2)
    return __builtin_amdgcn_fdot2(__builtin_bit_cast(h2v, a), __builtin_bit_cast(h2v, b), c, false);
#else
    __half2 ha = __builtin_bit_cast(__half2, a);
    __half2 hb = __builtin_bit_cast(__half2, b);
    return c + __low2float(ha) * __low2float(hb) + __high2float(ha) * __high2float(hb);
#endif
}
DEVINL unsigned int packh2(float a, float b) {
    __half2 h = __floats2half2_rn(a, b);
    return __builtin_bit_cast(unsigned int, h);
}
DEVINL unsigned short f2h16(float f) { return __builtin_bit_cast(unsigned short, (_Float16)f); }
DEVINL float h16f(unsigned short u) { return (float)__builtin_bit_cast(_Float16, u); }
DEVINL float sigmoidf_(float x) { return 1.0f / (1.0f + __expf(-x)); }
DEVINL float tanhf_(float x) { return 2.0f / (1.0f + __expf(-2.0f * x)) - 1.0f; }

// ---- packed-weight workspace layout (byte offsets, after X and hseq) ----
enum {
    WP_K1_FRAG = 0,        // 14 arrays * [256] half8
    WP_K1_BIAS = 57344,    // 2 arrays * [256] float4
    WP_K2_FRAG = 65536,    // 12 arrays * [512] half8
    WP_K2_BIAS = 163840,   // [512] float2
    WP_K4_FRAG = 167936,   // 2 arrays * [256] half8
    WP_K4_BIAS = 176128,   // [256] float
    WP_TOTAL = 177152
};

// ================= k0: one-shot weight fragment packing (grid 6) =================
__global__ __launch_bounds__(512) void k0_pack(
    const float* __restrict__ pe_w1, const float* __restrict__ pe_b1,
    const float* __restrict__ pe_w2, const float* __restrict__ pe_b2,
    const float* __restrict__ ee_w1, const float* __restrict__ ee_b1,
    const float* __restrict__ ee_w2, const float* __restrict__ ee_b2,
    const float* __restrict__ cb_w1, const float* __restrict__ cb_b1,
    const float* __restrict__ cb_w2, const float* __restrict__ cb_b2,
    const float* __restrict__ ih_w, const float* __restrict__ ih_b,
    const float* __restrict__ hh_w, const float* __restrict__ hh_b,
    const float* __restrict__ th_w, const float* __restrict__ th_b,
    const float* __restrict__ an_w, const float* __restrict__ an_b,
    const float* __restrict__ sh_w, const float* __restrict__ sh_b,
    const float* __restrict__ bo_w, const float* __restrict__ bo_b,
    char* __restrict__ Wp)
{
    const int t = threadIdx.x;
    const int bk = blockIdx.x;
    half8* f1 = (half8*)(Wp + WP_K1_FRAG);
    float4* b1v = (float4*)(Wp + WP_K1_BIAS);
    half8* f2 = (half8*)(Wp + WP_K2_FRAG);
    float2* b2v = (float2*)(Wp + WP_K2_BIAS);
    half8* f4 = (half8*)(Wp + WP_K4_FRAG);
    float* b4v = (float*)(Wp + WP_K4_BIAS);

    if (bk == 0) {
        if (t >= 256) return;
        const int l = t & 63, w = t >> 6;
        const int kof = (l >> 4) * 8;
        const int c16 = w * 16 + (l & 15);
        #pragma unroll
        for (int ct = 0; ct < 2; ct++) {
            int col = w * 32 + ct * 16 + (l & 15);
            #pragma unroll
            for (int kt = 0; kt < 2; kt++) {
                half8 v;
                #pragma unroll
                for (int j = 0; j < 8; j++) { int k = kt * 32 + kof + j; v[j] = (k < 63) ? (_Float16)cb_w1[k * 128 + col] : (_Float16)0.f; }
                f1[(ct * 2 + kt) * 256 + t] = v;
            }
        }
        #pragma unroll
        for (int kt = 0; kt < 4; kt++) {
            half8 v;
            #pragma unroll
            for (int j = 0; j < 8; j++) v[j] = (_Float16)cb_w2[(kt * 32 + kof + j) * 64 + c16];
            f1[(4 + kt) * 256 + t] = v;
        }
    } else if (bk == 1) {
        if (t >= 256) return;
        const int l = t & 63, w = t >> 6;
        const int kof = (l >> 4) * 8;
        const int c16 = w * 16 + (l & 15);
        {
            half8 v;
            #pragma unroll
            for (int j = 0; j < 8; j++) { int k = kof + j; v[j] = (k < 21) ? (_Float16)pe_w1[k * 64 + c16] : (_Float16)0.f; }
            f1[8 * 256 + t] = v;
        }
        #pragma unroll
        for (int kt = 0; kt < 2; kt++) {
            half8 v;
            #pragma unroll
            for (int j = 0; j < 8; j++) v[j] = (_Float16)pe_w2[(kt * 32 + kof + j) * 64 + c16];
            f1[(9 + kt) * 256 + t] = v;
        }
        #pragma unroll
        for (int ct = 0; ct < 2; ct++) {
            half8 v;
            #pragma unroll
            for (int j = 0; j < 8; j++) { int k = kof + j; v[j] = (k < 13) ? (_Float16)ee_w1[k * 32 + ct * 16 + (l & 15)] : (_Float16)0.f; }
            f1[(11 + ct) * 256 + t] = v;
        }
        {
            half8 v;
            #pragma unroll
            for (int j = 0; j < 8; j++) v[j] = (_Float16)ee_w2[(kof + j) * 16 + (l & 15)];
            f1[13 * 256 + t] = v;
        }
        float4 bb0, bb1;
        bb0.x = cb_b1[w * 32 + (l & 15)];
        bb0.y = cb_b1[w * 32 + 16 + (l & 15)];
        bb0.z = cb_b2[c16];
        bb0.w = pe_b1[c16];
        bb1.x = pe_b2[c16];
        bb1.y = ee_b1[l & 15];
        bb1.z = ee_b1[16 + (l & 15)];
        bb1.w = ee_b2[l & 15];
        b1v[t] = bb0;
        b1v[256 + t] = bb1;
    } else if (bk == 2 || bk == 3) {  // k2 fragments, ct = bk-2 (wave-local gate mapping)
        const int ct = bk - 2;
        const int l = t & 63, w = t >> 6;
        const int kof = (l >> 4) * 8;
        const int cc = ct * 16 + (l & 15);
        const int origc = (cc >> 3) * 64 + w * 8 + (cc & 7);
        #pragma unroll
        for (int kt = 0; kt < 4; kt++) {
            half8 v;
            #pragma unroll
            for (int j = 0; j < 8; j++) v[j] = (_Float16)ih_w[(kt * 32 + kof + j) * 256 + origc];
            f2[(ct * 4 + kt) * 512 + t] = v;
        }
        #pragma unroll
        for (int kt = 0; kt < 2; kt++) {
            half8 v;
            #pragma unroll
            for (int j = 0; j < 8; j++) v[j] = (_Float16)hh_w[(kt * 32 + kof + j) * 256 + origc];
            f2[(8 + ct * 2 + kt) * 512 + t] = v;
        }
        if (ct == 0) {
            const int cc1 = 16 + (l & 15);
            const int origc1 = (cc1 >> 3) * 64 + w * 8 + (cc1 & 7);
            float2 bb;
            bb.x = ih_b[origc] + hh_b[origc];
            bb.y = ih_b[origc1] + hh_b[origc1];
            b2v[t] = bb;
        }
    } else if (bk == 4) {
        if (t >= 256) return;
        const int l = t & 63;
        const int hc = l & 15;
        const int kof = (l >> 4) * 8;
        #pragma unroll
        for (int kt = 0; kt < 2; kt++) {
            half8 v;
            #pragma unroll
            for (int j = 0; j < 8; j++) {
                int k = kt * 32 + kof + j;
                float wv = 0.f;
                if (hc == 0) wv = th_w[k];
                else if (hc == 1) wv = an_w[k];
                else if (hc == 2) wv = sh_w[2 * k];
                else if (hc == 3) wv = sh_w[2 * k + 1];
                else if (hc == 4) wv = bo_w[2 * k];
                else if (hc == 5) wv = bo_w[2 * k + 1];
                v[j] = (_Float16)wv;
            }
            f4[kt * 256 + t] = v;
        }
        float bias = 0.f;
        if (hc == 0) bias = th_b[0];
        else if (hc == 1) bias = an_b[0];
        else if (hc == 2) bias = sh_b[0];
        else if (hc == 3) bias = sh_b[1];
        else if (hc == 4) bias = bo_b[0];
        else if (hc == 5) bias = bo_b[1];
        b4v[t] = bias;
    }
}

// ================= k1: all-MFMA encoders -> X[BS][128] f16 (31.7 KB LDS -> 5 blocks/CU) =================
// LDS map (bytes):
//   0      s_cin  [64][72]  f16
//   9216   s_pin  [64][40]  f16
//   14336  region A:
//     entity phase: 14336 s_einh [96][40] f16 | 22016 s_emidh [96][40] f16 | 29696 s_lat16 [192][17] f16 (overlaps s_mid区)
//     GEMM phase:   14336 s_mid  [64][136] f16 (G2/G4 C-fragments store DIRECTLY to global)
__global__ __launch_bounds__(256) void k1_encode(
    const float* __restrict__ self_obs, const float* __restrict__ tm_obs,
    const float* __restrict__ en_obs, const float* __restrict__ cp_obs,
    const int* __restrict__ role_ids, const float* __restrict__ role_emb,
    const char* __restrict__ Wp, unsigned int* __restrict__ Xg)
{
    __shared__ __align__(16) unsigned char s_raw[36224];
    __shared__ float eb[32];
    unsigned short* s_cin = (unsigned short*)(s_raw);
    unsigned short* s_pin = (unsigned short*)(s_raw + 9216);
    unsigned short* s_einh = (unsigned short*)(s_raw + 14336);
    unsigned short* s_emidh = (unsigned short*)(s_raw + 22016);
    unsigned short* s_lat16 = (unsigned short*)(s_raw + 29696);   // 192*17*2 = 6528 -> ends 36224
    unsigned short* s_mid = (unsigned short*)(s_raw + 14336);     // 64*136*2 = 17408 -> ends 31744

    const int t = threadIdx.x;
    const int l = t & 63, w = t >> 6;
    const long long row0 = (long long)blockIdx.x * 64;
    unsigned short* Xg16 = (unsigned short*)Xg;

    for (int i = t; i < 7424; i += 256) ((unsigned int*)s_raw)[i] = 0;
    if (t < 32) eb[t] = role_emb[t];

    const half8* f1 = (const half8*)(Wp + WP_K1_FRAG);
    const float4* b1v = (const float4*)(Wp + WP_K1_BIAS);
    half8 bL1[2][2], bL2[4], bP1, bP2[2], bE1[2], bE2;
    bL1[0][0] = f1[0 * 256 + t]; bL1[0][1] = f1[1 * 256 + t];
    bL1[1][0] = f1[2 * 256 + t]; bL1[1][1] = f1[3 * 256 + t];
    #pragma unroll
    for (int kt = 0; kt < 4; kt++) bL2[kt] = f1[(4 + kt) * 256 + t];
    bP1 = f1[8 * 256 + t];
    bP2[0] = f1[9 * 256 + t]; bP2[1] = f1[10 * 256 + t];
    bE1[0] = f1[11 * 256 + t]; bE1[1] = f1[12 * 256 + t];
    bE2 = f1[13 * 256 + t];
    float4 bb0 = b1v[t], bb1 = b1v[256 + t];
    float bsL1[2] = {bb0.x, bb0.y};
    float bsL2 = bb0.z, bsP1 = bb0.w, bsP2 = bb1.x;
    float bsE1[2] = {bb1.y, bb1.z};
    float bsE2 = bb1.w;
    __syncthreads();

    const int arow = l & 15;
    const int crow0 = (l >> 4) * 4;
    const int kof = (l >> 4) * 8;
    const int c16 = w * 16 + (l & 15);

    for (int idx = t; idx < 960; idx += 256) {
        int r = idx / 15, k = idx - r * 15;
        unsigned short hv = f2h16(self_obs[row0 * 15 + idx]);
        s_cin[r * 72 + k] = hv;
        s_pin[r * 40 + k] = hv;
    }
    for (int idx = t; idx < 384; idx += 256) {
        int r = idx / 6, k = idx - r * 6;
        s_pin[r * 40 + 15 + k] = f2h16(cp_obs[row0 * 6 + idx]);
    }

    #pragma unroll 1
    for (int p = 0; p < 2; p++) {
        for (int idx = t; idx < 416; idx += 256) {
            int r = idx / 13, k = idx - r * 13;
            s_einh[(3 * r) * 40 + k] = f2h16(tm_obs[(row0 + 32 * p) * 13 + idx]);
        }
        for (int idx = t; idx < 832; idx += 256) {
            int r = idx / 26, rem = idx - r * 26;
            int src = rem / 13, k = rem - src * 13;
            s_einh[(3 * r + 1 + src) * 40 + k] = f2h16(en_obs[(row0 + 32 * p) * 26 + idx]);
        }
        __syncthreads();
        #pragma unroll
        for (int i = 0; i < 2; i++) {
            int rt = w + i * 4;
            if (rt < 6) {
                half8 a = *(const half8*)(s_einh + (rt * 16 + arow) * 40 + kof);
                #pragma unroll
                for (int ct = 0; ct < 2; ct++) {
                    floatx4 acc = {bsE1[ct], bsE1[ct], bsE1[ct], bsE1[ct]};
                    acc = __builtin_amdgcn_mfma_f32_16x16x32_f16(a, bE1[ct], acc, 0, 0, 0);
                    #pragma unroll
                    for (int rr = 0; rr < 4; rr++)
                        s_emidh[(rt * 16 + crow0 + rr) * 40 + ct * 16 + (l & 15)] = f2h16(fmaxf(acc[rr], 0.f));
                }
            }
        }
        __syncthreads();
        #pragma unroll
        for (int i = 0; i < 2; i++) {
            int rt = w + i * 4;
            if (rt < 6) {
                half8 a = *(const half8*)(s_emidh + (rt * 16 + arow) * 40 + kof);
                floatx4 acc = {bsE2, bsE2, bsE2, bsE2};
                acc = __builtin_amdgcn_mfma_f32_16x16x32_f16(a, bE2, acc, 0, 0, 0);
                #pragma unroll
                for (int rr = 0; rr < 4; rr++)
                    s_lat16[(96 * p + rt * 16 + crow0 + rr) * 17 + (l & 15)] = f2h16(acc[rr]);
            }
        }
        __syncthreads();
    }

    {
        const int r = t >> 2, q = t & 3;
        int rid = role_ids[row0 + r];
        #pragma unroll
        for (int j = 0; j < 4; j++) {
            int o = q * 4 + j;
            unsigned short tm16 = s_lat16[(3 * r) * 17 + o];
            float e1f = h16f(s_lat16[(3 * r + 1) * 17 + o]);
            float e2f = h16f(s_lat16[(3 * r + 2) * 17 + o]);
            s_cin[r * 72 + 15 + o] = tm16;
            s_cin[r * 72 + 31 + o] = f2h16(fmaxf(e1f, e2f));
            s_cin[r * 72 + 47 + o] = f2h16(eb[rid * 16 + o]);
        }
    }
    __syncthreads();

    // ---- G1: cmd L1 (63->128 relu) -> s_mid ----
    #pragma unroll 1
    for (int rt = 0; rt < 4; rt++) {
        half8 a0 = *(const half8*)(s_cin + (rt * 16 + arow) * 72 + kof);
        half8 a1 = *(const half8*)(s_cin + (rt * 16 + arow) * 72 + 32 + kof);
        #pragma unroll
        for (int ct = 0; ct < 2; ct++) {
            floatx4 acc = {bsL1[ct], bsL1[ct], bsL1[ct], bsL1[ct]};
            acc = __builtin_amdgcn_mfma_f32_16x16x32_f16(a0, bL1[ct][0], acc, 0, 0, 0);
            acc = __builtin_amdgcn_mfma_f32_16x16x32_f16(a1, bL1[ct][1], acc, 0, 0, 0);
            int col = w * 32 + ct * 16 + (l & 15);
            #pragma unroll
            for (int rr = 0; rr < 4; rr++)
                s_mid[(rt * 16 + crow0 + rr) * 136 + col] = f2h16(fmaxf(acc[rr], 0.f));
        }
    }
    __syncthreads();
    // ---- G2: cmd L2 (128->64 relu) -> DIRECT global store (X cols 64..127) ----
    #pragma unroll 1
    for (int rt = 0; rt < 4; rt++) {
        floatx4 acc = {bsL2, bsL2, bsL2, bsL2};
        #pragma unroll
        for (int kt = 0; kt < 4; kt++) {
            half8 a = *(const half8*)(s_mid + (rt * 16 + arow) * 136 + kt * 32 + kof);
            acc = __builtin_amdgcn_mfma_f32_16x16x32_f16(a, bL2[kt], acc, 0, 0, 0);
        }
        #pragma unroll
        for (int rr = 0; rr < 4; rr++)
            Xg16[(row0 + rt * 16 + crow0 + rr) * 128 + 64 + c16] = f2h16(fmaxf(acc[rr], 0.f));
    }
    __syncthreads();  // all G2 reads of s_mid done before G3 overwrites
    // ---- G3: pilot L1 (21->64 relu) -> s_mid cols 0..63 ----
    #pragma unroll 1
    for (int rt = 0; rt < 4; rt++) {
        half8 a = *(const half8*)(s_pin + (rt * 16 + arow) * 40 + kof);
        floatx4 acc = {bsP1, bsP1, bsP1, bsP1};
        acc = __builtin_amdgcn_mfma_f32_16x16x32_f16(a, bP1, acc, 0, 0, 0);
        #pragma unroll
        for (int rr = 0; rr < 4; rr++)
            s_mid[(rt * 16 + crow0 + rr) * 136 + c16] = f2h16(fmaxf(acc[rr], 0.f));
    }
    __syncthreads();
    // ---- G4: pilot L2 (64->64 relu) -> DIRECT global store (X cols 0..63) ----
    #pragma unroll 1
    for (int rt = 0; rt < 4; rt++) {
        floatx4 acc = {bsP2, bsP2, bsP2, bsP2};
        #pragma unroll
        for (int kt = 0; kt < 2; kt++) {
            half8 a = *(const half8*)(s_mid + (rt * 16 + arow) * 136 + kt * 32 + kof);
            acc = __builtin_amdgcn_mfma_f32_16x16x32_f16(a, bP2[kt], acc, 0, 0, 0);
        }
        #pragma unroll
        for (int rr = 0; rr < 4; rr++)
            Xg16[(row0 + rt * 16 + crow0 + rr) * 128 + c16] = f2h16(fmaxf(acc[rr], 0.f));
    }
}

// ================= k2: MFMA LSTM — step-pair A-frames, transposed gate scratch (R18 proven) =================
__global__ __launch_bounds__(512) void k2_lstm(
    const char* __restrict__ Wp,
    const unsigned int* __restrict__ Xg, unsigned short* __restrict__ hseq,
    float* __restrict__ out)
{
    __shared__ __align__(16) unsigned short s_x[2][2][16][136];
    __shared__ __align__(16) unsigned short s_h[16][72];
    __shared__ __align__(16) float s_gwT[8][8][32];

    const int t = threadIdx.x;
    const int bb = blockIdx.x;
    const int l = t & 63;
    const int w = t >> 6;

    {
        unsigned int* z = (unsigned int*)&s_x[0][0][0][0];
        for (int i = t; i < 4352; i += 512) z[i] = 0;
        unsigned int* z2 = (unsigned int*)&s_h[0][0];
        for (int i = t; i < 576; i += 512) z2[i] = 0;
    }

    const int kof = (l >> 4) * 8;
    const half8* f2 = (const half8*)(Wp + WP_K2_FRAG);
    const float2* b2v = (const float2*)(Wp + WP_K2_BIAS);
    half8 bx[2][4], bh[2][2];
    #pragma unroll
    for (int ct = 0; ct < 2; ct++) {
        #pragma unroll
        for (int kt = 0; kt < 4; kt++) bx[ct][kt] = f2[(ct * 4 + kt) * 512 + t];
        #pragma unroll
        for (int kt = 0; kt < 2; kt++) bh[ct][kt] = f2[(8 + ct * 2 + kt) * 512 + t];
    }
    float2 bbv = b2v[t];
    float biasv[2] = {bbv.x, bbv.y};

    const int step_ld = t >> 7;
    const int r_ld = (t >> 4) & 7;
    const int seg = t & 15;
    const int dst_pair = step_ld >> 1;
    const int dst_row = 8 * (step_ld & 1) + r_ld;
    const long long gb0 = (long long)bb * 8;
    uint4 p;

    __syncthreads();
    {
        const unsigned int* src = Xg + ((gb0 + r_ld) * Sn + step_ld) * 64 + seg * 4;
        p = *(const uint4*)src;
        *(uint4*)((unsigned int*)&s_x[0][dst_pair][dst_row][0] + seg * 4) = p;
    }
    __syncthreads();
    {
        const unsigned int* src = Xg + ((gb0 + r_ld) * Sn + (4 + step_ld)) * 64 + seg * 4;
        p = *(const uint4*)src;
    }

    const int arow = l & 15;
    const int urow = l >> 3;
    const int ul = l & 7;
    const int pside = (l >> 5) & 1;
    const int cc0 = l & 15;
    const int rbase = ((l >> 4) & 1) * 4;
    float cst = 0.f, hst = 0.f;

    #pragma unroll 1
    for (int c = 0; c < 64; c++) {
        const int buf = c & 1;
        floatx4 wxa[2][2];
        #pragma unroll
        for (int sl2 = 0; sl2 < 2; sl2++) {
            half8 xa0 = *(const half8*)&s_x[buf][sl2][arow][kof];
            half8 xa1 = *(const half8*)&s_x[buf][sl2][arow][32 + kof];
            half8 xa2 = *(const half8*)&s_x[buf][sl2][arow][64 + kof];
            half8 xa3 = *(const half8*)&s_x[buf][sl2][arow][96 + kof];
            floatx4 a0 = {biasv[0], biasv[0], biasv[0], biasv[0]};
            floatx4 a1 = {biasv[1], biasv[1], biasv[1], biasv[1]};
            a0 = __builtin_amdgcn_mfma_f32_16x16x32_f16(xa0, bx[0][0], a0, 0, 0, 0);
            a1 = __builtin_amdgcn_mfma_f32_16x16x32_f16(xa0, bx[1][0], a1, 0, 0, 0);
            a0 = __builtin_amdgcn_mfma_f32_16x16x32_f16(xa1, bx[0][1], a0, 0, 0, 0);
            a1 = __builtin_amdgcn_mfma_f32_16x16x32_f16(xa1, bx[1][1], a1, 0, 0, 0);
            a0 = __builtin_amdgcn_mfma_f32_16x16x32_f16(xa2, bx[0][2], a0, 0, 0, 0);
            a1 = __builtin_amdgcn_mfma_f32_16x16x32_f16(xa2, bx[1][2], a1, 0, 0, 0);
            a0 = __builtin_amdgcn_mfma_f32_16x16x32_f16(xa3, bx[0][3], a0, 0, 0, 0);
            a1 = __builtin_amdgcn_mfma_f32_16x16x32_f16(xa3, bx[1][3], a1, 0, 0, 0);
            wxa[sl2][0] = a0;
            wxa[sl2][1] = a1;
        }
        #pragma unroll
        for (int sl = 0; sl < 4; sl++) {
            const int sl2 = sl >> 1;
            const int odd = sl & 1;
            half8 hA0 = *(const half8*)&s_h[arow][kof];
            half8 hA1 = *(const half8*)&s_h[arow][32 + kof];
            floatx4 acc0 = wxa[sl2][0];
            floatx4 acc1 = wxa[sl2][1];
            acc0 = __builtin_amdgcn_mfma_f32_16x16x32_f16(hA0, bh[0][0], acc0, 0, 0, 0);
            acc1 = __builtin_amdgcn_mfma_f32_16x16x32_f16(hA0, bh[1][0], acc1, 0, 0, 0);
            acc0 = __builtin_amdgcn_mfma_f32_16x16x32_f16(hA1, bh[0][1], acc0, 0, 0, 0);
            acc1 = __builtin_amdgcn_mfma_f32_16x16x32_f16(hA1, bh[1][1], acc1, 0, 0, 0);
            if (pside == odd) {
                const int ga = cc0 >> 3;
                const int up = cc0 & 7;
                #pragma unroll
                for (int rr = 0; rr < 4; rr++) {
                    s_gwT[w][rbase + rr][up * 4 + ga] = acc0[rr];
                    s_gwT[w][rbase + rr][up * 4 + 2 + ga] = acc1[rr];
                }
            }
            __builtin_amdgcn_wave_barrier();
            {
                const float4 gv = *(const float4*)&s_gwT[w][urow][ul * 4];
                float i_ = sigmoidf_(gv.x), f_ = sigmoidf_(gv.y);
                float g_ = tanhf_(gv.z), o_ = sigmoidf_(gv.w);
                cst = f_ * cst + i_ * g_;
                hst = o_ * tanhf_(cst);
                unsigned short h16 = f2h16(hst);
                s_h[urow][w * 8 + ul] = h16;
                s_h[8 + urow][w * 8 + ul] = h16;
                hseq[((gb0 + urow) * Sn + (c * 4 + sl)) * 64 + w * 8 + ul] = h16;
            }
            if (sl == 3 && c < 63)
                *(uint4*)((unsigned int*)&s_x[buf ^ 1][dst_pair][dst_row][0] + seg * 4) = p;
            __syncthreads();
        }
        if (c < 62) {
            const unsigned int* src = Xg + ((gb0 + r_ld) * Sn + ((c + 2) * 4 + step_ld)) * 64 + seg * 4;
            p = *(const uint4*)src;
        }
    }
    float* hn = out + 8 * BSn;
    float* cn = hn + (long long)Bn * 64;
    hn[(gb0 + urow) * 64 + w * 8 + ul] = hst;
    cn[(gb0 + urow) * 64 + w * 8 + ul] = cst;
}

// ================= k4: heads (MFMA over hseq) + std fill =================
__global__ __launch_bounds__(256) void k4_heads(
    const unsigned short* __restrict__ hseq, const char* __restrict__ Wp,
    const float* __restrict__ logstd, float* __restrict__ out)
{
    const int t = threadIdx.x, l = t & 63, w = t >> 6;
    const long long row0 = (long long)blockIdx.x * 64 + w * 16;
    const int hc = l & 15;
    const int kof = (l >> 4) * 8;
    const half8* f4 = (const half8*)(Wp + WP_K4_FRAG);
    half8 bhd0 = f4[t], bhd1 = f4[256 + t];
    float bias = ((const float*)(Wp + WP_K4_BIAS))[t];
    const unsigned short* hp = hseq + (row0 + (l & 15)) * 64;
    half8 a0 = *(const half8*)(hp + kof);
    half8 a1 = *(const half8*)(hp + 32 + kof);
    floatx4 acc = {bias, bias, bias, bias};
    acc = __builtin_amdgcn_mfma_f32_16x16x32_f16(a0, bhd0, acc, 0, 0, 0);
    acc = __builtin_amdgcn_mfma_f32_16x16x32_f16(a1, bhd1, acc, 0, 0, 0);
    float s0 = fmaxf(__expf(logstd[0]), 0.05f);
    float s1 = fmaxf(__expf(logstd[1]), 0.05f);
    #pragma unroll
    for (int rr = 0; rr < 4; rr++) {
        long long row = row0 + (l >> 4) * 4 + rr;
        float v = acc[rr];
        if (hc == 0)      out[row] = sigmoidf_(v);
        else if (hc == 1) out[BSn + row] = tanhf_(v);
        else if (hc == 2) out[4 * BSn + 2 * row] = v;
        else if (hc == 3) out[4 * BSn + 2 * row + 1] = v;
        else if (hc == 4) out[6 * BSn + 2 * row] = v;
        else if (hc == 5) out[6 * BSn + 2 * row + 1] = v;
        else if (hc == 6) out[2 * BSn + 2 * row] = s0;
        else if (hc == 7) out[2 * BSn + 2 * row + 1] = s1;
    }
}

// ================= fallback: monolithic (R3 structure, proven @1454us) =================
enum {
    O_PE1 = 0, O_PE2 = 768, O_EE1 = 2816, O_EE2 = 3072,
    O_CB1 = 3328, O_CB2 = 7424, O_BIAS = 11520
};
__global__ __launch_bounds__(256)
void k_fallback(
    const float* __restrict__ self_obs, const float* __restrict__ tm_obs,
    const float* __restrict__ en_obs, const float* __restrict__ cp_obs,
    const int* __restrict__ role_ids,
    const float* __restrict__ pe_w1, const float* __restrict__ pe_b1,
    const float* __restrict__ pe_w2, const float* __restrict__ pe_b2,
    const float* __restrict__ role_emb,
    const float* __restrict__ ee_w1, const float* __restrict__ ee_b1,
    const float* __restrict__ ee_w2, const float* __restrict__ ee_b2,
    const float* __restrict__ cb_w1, const float* __restrict__ cb_b1,
    const float* __restrict__ cb_w2, const float* __restrict__ cb_b2,
    const float* __restrict__ ih_w, const float* __restrict__ ih_b,
    const float* __restrict__ hh_w, const float* __restrict__ hh_b,
    const float* __restrict__ th_w, const float* __restrict__ th_b,
    const float* __restrict__ an_w, const float* __restrict__ an_b,
    const float* __restrict__ sh_w, const float* __restrict__ sh_b,
    const float* __restrict__ bo_w, const float* __restrict__ bo_b,
    const float* __restrict__ logstd, float* __restrict__ out)
{
    __shared__ __align__(16) unsigned int s_tile[Sn * 64];
    __shared__ __align__(16) unsigned int s_h32[32];
    __shared__ float s_g[192];
    __shared__ unsigned int s_hw[192];
    __shared__ float s_hb[8];

    const int t = threadIdx.x;
    const int b = blockIdx.x;

    for (int i = t; i < 768; i += 256) {
        int o = i / 12, m = i % 12, k0 = 2 * m, k1 = k0 + 1;
        float a = (k0 < 21) ? pe_w1[k0 * 64 + o] : 0.f;
        float c = (k1 < 21) ? pe_w1[k1 * 64 + o] : 0.f;
        s_tile[O_PE1 + i] = packh2(a, c);
    }
    for (int i = t; i < 2048; i += 256) {
        int o = i >> 5, m = i & 31;
        s_tile[O_PE2 + i] = packh2(pe_w2[(2 * m) * 64 + o], pe_w2[(2 * m + 1) * 64 + o]);
    }
    {
        int i = t;
        int o = i >> 3, m = i & 7, k0 = 2 * m, k1 = k0 + 1;
        float a = (k0 < 13) ? ee_w1[k0 * 32 + o] : 0.f;
        float c = (k1 < 13) ? ee_w1[k1 * 32 + o] : 0.f;
        s_tile[O_EE1 + i] = packh2(a, c);
    }
    {
        int i = t;
        int o = i >> 4, m = i & 15;
        s_tile[O_EE2 + i] = packh2(ee_w2[(2 * m) * 16 + o], ee_w2[(2 * m + 1) * 16 + o]);
    }
    for (int i = t; i < 4096; i += 256) {
        int o = i >> 5, m = i & 31, k0 = 2 * m, k1 = k0 + 1;
        float a = (k0 < 63) ? cb_w1[k0 * 128 + o] : 0.f;
        float c = (k1 < 63) ? cb_w1[k1 * 128 + o] : 0.f;
        s_tile[O_CB1 + i] = packh2(a, c);
    }
    for (int i = t; i < 4096; i += 256) {
        int o = i >> 6, m = i & 63;
        s_tile[O_CB2 + i] = packh2(cb_w2[(2 * m) * 64 + o], cb_w2[(2 * m + 1) * 64 + o]);
    }
    float* bias = (float*)(s_tile + O_BIAS);
    if (t < 64) bias[t] = pe_b1[t];
    if (t < 64) bias[64 + t] = pe_b2[t];
    if (t < 32) bias[128 + t] = ee_b1[t];
    if (t < 16) bias[160 + t] = ee_b2[t];
    if (t < 128) bias[176 + t] = cb_b1[t];
    if (t < 64) bias[304 + t] = cb_b2[t];
    if (t < 32) bias[368 + t] = role_emb[t];
    if (t < 32)        s_hw[t]        = packh2(th_w[2 * t], th_w[2 * t + 1]);
    else if (t < 64)  { int m = t - 32;  s_hw[32 + m]  = packh2(an_w[2 * m], an_w[2 * m + 1]); }
    else if (t < 96)  { int m = t - 64;  s_hw[64 + m]  = packh2(sh_w[4 * m], sh_w[4 * m + 2]); }
    else if (t < 128) { int m = t - 96;  s_hw[96 + m]  = packh2(sh_w[4 * m + 1], sh_w[4 * m + 3]); }
    else if (t < 160) { int m = t - 128; s_hw[128 + m] = packh2(bo_w[4 * m], bo_w[4 * m + 2]); }
    else if (t < 192) { int m = t - 160; s_hw[160 + m] = packh2(bo_w[4 * m + 1], bo_w[4 * m + 3]); }
    if (t == 0) {
        s_hb[0] = th_b[0]; s_hb[1] = an_b[0];
        s_hb[2] = sh_b[0]; s_hb[3] = sh_b[1];
        s_hb[4] = bo_b[0]; s_hb[5] = bo_b[1];
        s_hb[6] = fmaxf(__expf(logstd[0]), 0.05f);
        s_hb[7] = fmaxf(__expf(logstd[1]), 0.05f);
    }
    if (t < 32) s_h32[t] = 0u;
    __syncthreads();

    {
        const long long row = (long long)b * Sn + t;
        float lat[32];
        #pragma unroll 1
        for (int src = 0; src < 3; src++) {
            const float* xp = (src == 0) ? (tm_obs + row * 13) : (en_obs + row * 26 + (src - 1) * 13);
            unsigned int xpr[8];
            #pragma unroll
            for (int m = 0; m < 8; m++) {
                int k0 = 2 * m, k1 = k0 + 1;
                xpr[m] = packh2((k0 < 13) ? xp[k0] : 0.f, (k1 < 13) ? xp[k1] : 0.f);
            }
            unsigned int e1[16];
            #pragma unroll
            for (int o2 = 0; o2 < 16; o2++) {
                float a0 = bias[128 + 2 * o2], a1 = bias[128 + 2 * o2 + 1];
                const unsigned int* w0 = s_tile + O_EE1 + (2 * o2) * 8;
                #pragma unroll
                for (int m = 0; m < 8; m++) { a0 = dot2(xpr[m], w0[m], a0); a1 = dot2(xpr[m], w0[8 + m], a1); }
                e1[o2] = packh2(fmaxf(a0, 0.f), fmaxf(a1, 0.f));
            }
            #pragma unroll
            for (int o = 0; o < 16; o++) {
                float a0 = bias[160 + o];
                const unsigned int* w0 = s_tile + O_EE2 + o * 16;
                #pragma unroll
                for (int m = 0; m < 16; m++) a0 = dot2(e1[m], w0[m], a0);
                if (src == 0) lat[o] = a0;
                else if (src == 1) lat[16 + o] = a0;
                else lat[16 + o] = fmaxf(lat[16 + o], a0);
            }
        }
        unsigned int cpp[32];
        {
            const float* sp = self_obs + row * 15;
            const int rid = role_ids[row];
            const float* rvec = bias + 368 + rid * 16;
            #pragma unroll
            for (int m = 0; m < 32; m++) {
                int k0 = 2 * m, k1 = k0 + 1;
                float a = (k0 < 15) ? sp[k0] : (k0 < 31) ? lat[k0 - 15] : (k0 < 47) ? lat[16 + k0 - 31] : rvec[k0 - 47];
                float c = (k1 < 15) ? sp[k1] : (k1 < 31) ? lat[k1 - 15] : (k1 < 47) ? lat[16 + k1 - 31]
                                                                       : (k1 < 63) ? rvec[k1 - 47] : 0.f;
                cpp[m] = packh2(a, c);
            }
        }
        unsigned int c1[64];
        #pragma unroll
        for (int o2 = 0; o2 < 64; o2++) {
            float a0 = bias[176 + 2 * o2], a1 = bias[176 + 2 * o2 + 1];
            const unsigned int* w0 = s_tile + O_CB1 + (2 * o2) * 32;
            #pragma unroll
            for (int m = 0; m < 32; m++) { a0 = dot2(cpp[m], w0[m], a0); a1 = dot2(cpp[m], w0[32 + m], a1); }
            c1[o2] = packh2(fmaxf(a0, 0.f), fmaxf(a1, 0.f));
        }
        unsigned int resc[32];
        #pragma unroll
        for (int o2 = 0; o2 < 32; o2++) {
            float a0 = bias[304 + 2 * o2], a1 = bias[304 + 2 * o2 + 1];
            const unsigned int* w0 = s_tile + O_CB2 + (2 * o2) * 64;
            #pragma unroll
            for (int m = 0; m < 64; m++) { a0 = dot2(c1[m], w0[m], a0); a1 = dot2(c1[m], w0[64 + m], a1); }
            resc[o2] = packh2(fmaxf(a0, 0.f), fmaxf(a1, 0.f));
        }
        unsigned int inp[12];
        {
            const float* sp = self_obs + row * 15;
            const float* cp = cp_obs + row * 6;
            #pragma unroll
            for (int m = 0; m < 12; m++) {
                int k0 = 2 * m, k1 = k0 + 1;
                float a = (k0 < 15) ? sp[k0] : ((k0 < 21) ? cp[k0 - 15] : 0.f);
                float c = (k1 < 15) ? sp[k1] : ((k1 < 21) ? cp[k1 - 15] : 0.f);
                inp[m] = packh2(a, c);
            }
        }
        unsigned int r1p[32];
        #pragma unroll
        for (int o2 = 0; o2 < 32; o2++) {
            float a0 = bias[2 * o2], a1 = bias[2 * o2 + 1];
            const unsigned int* w0 = s_tile + O_PE1 + (2 * o2) * 12;
            #pragma unroll
            for (int m = 0; m < 12; m++) { a0 = dot2(inp[m], w0[m], a0); a1 = dot2(inp[m], w0[12 + m], a1); }
            r1p[o2] = packh2(fmaxf(a0, 0.f), fmaxf(a1, 0.f));
        }
        unsigned int resp[32];
        #pragma unroll
        for (int o2 = 0; o2 < 32; o2++) {
            float a0 = bias[64 + 2 * o2], a1 = bias[64 + 2 * o2 + 1];
            const unsigned int* w0 = s_tile + O_PE2 + (2 * o2) * 32;
            #pragma unroll
            for (int m = 0; m < 32; m++) { a0 = dot2(r1p[m], w0[m], a0); a1 = dot2(r1p[m], w0[32 + m], a1); }
            resp[o2] = packh2(fmaxf(a0, 0.f), fmaxf(a1, 0.f));
        }
        __syncthreads();
        uint4* rt4 = reinterpret_cast<uint4*>(s_tile + t * 64);
        #pragma unroll
        for (int q = 0; q < 8; q++)
            rt4[q] = make_uint4(resp[4 * q], resp[4 * q + 1], resp[4 * q + 2], resp[4 * q + 3]);
        #pragma unroll
        for (int q = 0; q < 8; q++)
            rt4[8 + q] = make_uint4(resc[4 * q], resc[4 * q + 1], resc[4 * q + 2], resc[4 * q + 3]);
    }

    unsigned int wih[64], whh[32];
    #pragma unroll
    for (int m = 0; m < 64; m++) wih[m] = packh2(ih_w[(2 * m) * 256 + t], ih_w[(2 * m + 1) * 256 + t]);
    #pragma unroll
    for (int m = 0; m < 32; m++) whh[m] = packh2(hh_w[(2 * m) * 256 + t], hh_w[(2 * m + 1) * 256 + t]);
    const float bias_t = ih_b[t] + hh_b[t];
    __syncthreads();

    const int grp = t >> 6;
    const int u = t & 63;
    float c = 0.f, h = 0.f, i_act = 0.f;
    #pragma unroll 1
    for (int s = 0; s < Sn; s++) {
        float acc = bias_t;
        const uint4* rq = reinterpret_cast<const uint4*>(s_tile + s * 64);
        #pragma unroll
        for (int q = 0; q < 16; q++) {
            uint4 rv = rq[q];
            acc = dot2(rv.x, wih[4 * q + 0], acc);
            acc = dot2(rv.y, wih[4 * q + 1], acc);
            acc = dot2(rv.z, wih[4 * q + 2], acc);
            acc = dot2(rv.w, wih[4 * q + 3], acc);
        }
        const uint4* hq = reinterpret_cast<const uint4*>(s_h32);
        #pragma unroll
        for (int q = 0; q < 8; q++) {
            uint4 hvv = hq[q];
            acc = dot2(hvv.x, whh[4 * q + 0], acc);
            acc = dot2(hvv.y, whh[4 * q + 1], acc);
            acc = dot2(hvv.z, whh[4 * q + 2], acc);
            acc = dot2(hvv.w, whh[4 * q + 3], acc);
        }
        float act = (grp == 2) ? tanhf_(acc) : sigmoidf_(acc);
        if (grp == 0) i_act = act; else s_g[t - 64] = act;
        __syncthreads();
        if (t < 64) {
            float f_ = s_g[u], g_ = s_g[64 + u], o_ = s_g[128 + u];
            c = f_ * c + i_act * g_;
            h = o_ * tanhf_(c);
            float hnext = __shfl_down(h, 1);
            if ((u & 1) == 0) {
                unsigned int hp = packh2(h, hnext);
                s_h32[u >> 1] = hp;
                s_tile[s * 64 + (((u >> 1) + s) & 31)] = hp;
            }
        }
        __syncthreads();
    }
    {
        const int w = t >> 6, lq = t & 63;
        const int m0 = (lq & 7) * 4;
        const int j0 = lq & 7;
        #pragma unroll 1
        for (int p = 0; p < 8; p++) {
            int s = w * 64 + p * 8 + (lq >> 3);
            float ath = 0.f, aan = 0.f, as0 = 0.f, as1 = 0.f, ab0 = 0.f, ab1 = 0.f;
            #pragma unroll
            for (int j = 0; j < 4; j++) {
                int m = m0 + j;
                unsigned int hvv = s_tile[s * 64 + ((m + s) & 31)];
                ath = dot2(hvv, s_hw[m], ath);
                aan = dot2(hvv, s_hw[32 + m], aan);
                as0 = dot2(hvv, s_hw[64 + m], as0);
                as1 = dot2(hvv, s_hw[96 + m], as1);
                ab0 = dot2(hvv, s_hw[128 + m], ab0);
                ab1 = dot2(hvv, s_hw[160 + m], ab1);
            }
            #pragma unroll
            for (int d = 1; d < 8; d <<= 1) {
                ath += __shfl_xor(ath, d); aan += __shfl_xor(aan, d);
                as0 += __shfl_xor(as0, d); as1 += __shfl_xor(as1, d);
                ab0 += __shfl_xor(ab0, d); ab1 += __shfl_xor(ab1, d);
            }
            long long row = (long long)b * Sn + s;
            if (j0 == 0)      out[row] = sigmoidf_(ath + s_hb[0]);
            else if (j0 == 1) out[BSn + row] = tanhf_(aan + s_hb[1]);
            else if (j0 == 2) out[2 * BSn + 2 * row] = s_hb[6];
            else if (j0 == 3) out[2 * BSn + 2 * row + 1] = s_hb[7];
            else if (j0 == 4) out[4 * BSn + 2 * row] = as0 + s_hb[2];
            else if (j0 == 5) out[4 * BSn + 2 * row + 1] = as1 + s_hb[3];
            else if (j0 == 6) out[6 * BSn + 2 * row] = ab0 + s_hb[4];
            else              out[6 * BSn + 2 * row + 1] = ab1 + s_hb[5];
        }
    }
    if (t < 64) {
        float* hn = out + 8 * BSn;
        float* cn = hn + (long long)Bn * 64;
        hn[(long long)b * 64 + u] = h;
        cn[(long long)b * 64 + u] = c;
    }
}

// ================= host =================
extern "C" void kernel_launch(void* const* d_in, const int* in_sizes, int n_in,
                              void* d_out, int out_size, void* d_ws, size_t ws_size,
                              hipStream_t stream)
{
    (void)in_sizes; (void)n_in; (void)out_size;
    float* out = (float*)d_out;
    const size_t X_BYTES = (size_t)BSn * 64 * 4;  // 134 MB (f16 pairs as u32)
    const size_t H_BYTES = (size_t)BSn * 64 * 2;  // 67 MB hseq f16

    if (d_ws != nullptr && ws_size >= X_BYTES + H_BYTES + WP_TOTAL) {
        unsigned int* Xg = (unsigned int*)d_ws;
        unsigned short* hseq = (unsigned short*)((char*)d_ws + X_BYTES);
        char* Wp = (char*)d_ws + X_BYTES + H_BYTES;
        k0_pack<<<6, 512, 0, stream>>>(
            (const float*)d_in[5], (const float*)d_in[6], (const float*)d_in[7], (const float*)d_in[8],
            (const float*)d_in[10], (const float*)d_in[11], (const float*)d_in[12], (const float*)d_in[13],
            (const float*)d_in[14], (const float*)d_in[15], (const float*)d_in[16], (const float*)d_in[17],
            (const float*)d_in[18], (const float*)d_in[19], (const float*)d_in[20], (const float*)d_in[21],
            (const float*)d_in[22], (const float*)d_in[23], (const float*)d_in[24], (const float*)d_in[25],
            (const float*)d_in[26], (const float*)d_in[27], (const float*)d_in[28], (const float*)d_in[29],
            Wp);
        k1_encode<<<(int)(BSn / 64), 256, 0, stream>>>(
            (const float*)d_in[0], (const float*)d_in[1], (const float*)d_in[2],
            (const float*)d_in[3], (const int*)d_in[4], (const float*)d_in[9],
            Wp, Xg);
        k2_lstm<<<Bn / 8, 512, 0, stream>>>(Wp, Xg, hseq, out);
        k4_heads<<<(int)(BSn / 64), 256, 0, stream>>>(hseq, Wp, (const float*)d_in[30], out);
    } else {
        k_fallback<<<Bn, 256, 0, stream>>>(
            (const float*)d_in[0], (const float*)d_in[1], (const float*)d_in[2],
            (const float*)d_in[3], (const int*)d_in[4],
            (const float*)d_in[5], (const float*)d_in[6], (const float*)d_in[7], (const float*)d_in[8],
            (const float*)d_in[9],
            (const float*)d_in[10], (const float*)d_in[11], (const float*)d_in[12], (const float*)d_in[13],
            (const float*)d_in[14], (const float*)d_in[15], (const float*)d_in[16], (const float*)d_in[17],
            (const float*)d_in[18], (const float*)d_in[19], (const float*)d_in[20], (const float*)d_in[21],
            (const float*)d_in[22], (const float*)d_in[23], (const float*)d_in[24], (const float*)d_in[25],
            (const float*)d_in[26], (const float*)d_in[27], (const float*)d_in[28], (const float*)d_in[29],
            (const float*)d_in[30], out);
    }
}